// Round 3
// baseline (894.254 us; speedup 1.0000x reference)
//
#include <hip/hip_runtime.h>
#include <stdint.h>
#include <math.h>

typedef unsigned short u16;
typedef __bf16 bf16x8 __attribute__((ext_vector_type(8)));
typedef float f32x4 __attribute__((ext_vector_type(4)));
typedef short s16x8 __attribute__((ext_vector_type(8)));
union B8 { s16x8 s; bf16x8 b; };

// ---------- helpers ----------
__device__ __forceinline__ u16 f2bf(float f) {
    uint32_t u = __float_as_uint(f);
    u += 0x7FFFu + ((u >> 16) & 1u);   // round-to-nearest-even
    return (u16)(u >> 16);
}
__device__ __forceinline__ uint32_t pkbf(float a, float b) {
    return (uint32_t)f2bf(a) | ((uint32_t)f2bf(b) << 16);
}

typedef const __attribute__((address_space(1))) uint32_t* gas_t;
typedef __attribute__((address_space(3))) uint32_t* las_t;
__device__ __forceinline__ void gld16(const void* g, void* l) {
    __builtin_amdgcn_global_load_lds((gas_t)g, (las_t)l, 16, 0, 0);
}

__host__ __device__ __forceinline__ uint32_t rotl32(uint32_t x, int d) {
    return (x << d) | (x >> (32 - d));
}

// JAX threefry2x32 (20 rounds)
__host__ __device__ __forceinline__ void tf2x32(uint32_t k0, uint32_t k1,
                                                uint32_t& x0, uint32_t& x1) {
    uint32_t k2 = k0 ^ k1 ^ 0x1BD11BDAu;
    x0 += k0; x1 += k1;
    x0 += x1; x1 = rotl32(x1, 13); x1 ^= x0;
    x0 += x1; x1 = rotl32(x1, 15); x1 ^= x0;
    x0 += x1; x1 = rotl32(x1, 26); x1 ^= x0;
    x0 += x1; x1 = rotl32(x1,  6); x1 ^= x0;
    x0 += k1; x1 += k2 + 1u;
    x0 += x1; x1 = rotl32(x1, 17); x1 ^= x0;
    x0 += x1; x1 = rotl32(x1, 29); x1 ^= x0;
    x0 += x1; x1 = rotl32(x1, 16); x1 ^= x0;
    x0 += x1; x1 = rotl32(x1, 24); x1 ^= x0;
    x0 += k2; x1 += k0 + 2u;
    x0 += x1; x1 = rotl32(x1, 13); x1 ^= x0;
    x0 += x1; x1 = rotl32(x1, 15); x1 ^= x0;
    x0 += x1; x1 = rotl32(x1, 26); x1 ^= x0;
    x0 += x1; x1 = rotl32(x1,  6); x1 ^= x0;
    x0 += k0; x1 += k1 + 3u;
    x0 += x1; x1 = rotl32(x1, 17); x1 ^= x0;
    x0 += x1; x1 = rotl32(x1, 29); x1 ^= x0;
    x0 += x1; x1 = rotl32(x1, 16); x1 ^= x0;
    x0 += x1; x1 = rotl32(x1, 24); x1 ^= x0;
    x0 += k1; x1 += k2 + 4u;
    x0 += x1; x1 = rotl32(x1, 13); x1 ^= x0;
    x0 += x1; x1 = rotl32(x1, 15); x1 ^= x0;
    x0 += x1; x1 = rotl32(x1, 26); x1 ^= x0;
    x0 += x1; x1 = rotl32(x1,  6); x1 ^= x0;
    x0 += k2; x1 += k0 + 5u;
}

// XLA ErfInv f32 (Giles polynomial)
__device__ __forceinline__ float erfinv_f(float x) {
    float w = -log1pf(-x * x);
    float p;
    if (w < 5.0f) {
        w = w - 2.5f;
        p = 2.81022636e-08f;
        p = p * w + 3.43273939e-07f;
        p = p * w + -3.5233877e-06f;
        p = p * w + -4.39150654e-06f;
        p = p * w + 0.00021858087f;
        p = p * w + -0.00125372503f;
        p = p * w + -0.00417768164f;
        p = p * w + 0.246640727f;
        p = p * w + 1.50140941f;
    } else {
        w = sqrtf(w) - 3.0f;
        p = -0.000200214257f;
        p = p * w + 0.000100950558f;
        p = p * w + 0.00134934322f;
        p = p * w + -0.00367342844f;
        p = p * w + 0.00573950773f;
        p = p * w + -0.0076224613f;
        p = p * w + 0.00943887047f;
        p = p * w + 1.00167406f;
        p = p * w + 2.83297682f;
    }
    return p * x;
}

__device__ __forceinline__ float tf_normal(uint32_t k0, uint32_t k1, uint32_t idx) {
    uint32_t x0 = 0u, x1 = idx;
    tf2x32(k0, k1, x0, x1);
    uint32_t bits = x0 ^ x1;
    float f = __uint_as_float((bits >> 9) | 0x3f800000u) - 1.0f;
    float u = f * 2.0f - 0.99999994f;
    u = fmaxf(-0.99999994f, u);
    return 1.41421354f * erfinv_f(u);
}

// ---------- noise init ----------
__global__ __launch_bounds__(256) void noise_kernel(
    float* __restrict__ x, u16* __restrict__ xb,
    uint32_t ka0, uint32_t ka1, float ca,
    uint32_t kb0, uint32_t kb1, float cb, int n)
{
    int i = blockIdx.x * 256 + threadIdx.x;
    if (i >= n) return;
    float a = ca * tf_normal(ka0, ka1, (uint32_t)i)
            + cb * tf_normal(kb0, kb1, (uint32_t)i);
    x[i]  = a;
    xb[i] = f2bf(a);
}

// ---------- f32 -> bf16 convert ----------
__global__ __launch_bounds__(256) void cvt_bf16_kernel(
    const float* __restrict__ s, u16* __restrict__ d, int n4)
{
    int i = blockIdx.x * 256 + threadIdx.x;
    if (i >= n4) return;
    float4 v = ((const float4*)s)[i];
    ushort4 o;
    o.x = f2bf(v.x); o.y = f2bf(v.y); o.z = f2bf(v.z); o.w = f2bf(v.w);
    ((ushort4*)d)[i] = o;
}

// ---------- build combined QKV weight [L][1536][512] bf16 ----------
__global__ __launch_bounds__(256) void cvt_qkvw_kernel(
    const float* __restrict__ Wq, const float* __restrict__ Wk,
    const float* __restrict__ Wv, u16* __restrict__ dst, int n4)
{
    int i = blockIdx.x * 256 + threadIdx.x;
    if (i >= n4) return;
    int e = i * 4;
    int l = e / 786432;
    int rem = e - l * 786432;
    int sel = rem >> 18;
    int off = rem & 262143;
    const float* src = (sel == 0 ? Wq : sel == 1 ? Wk : Wv) + l * 262144 + off;
    float4 v = *(const float4*)src;
    ushort4 o;
    o.x = f2bf(v.x); o.y = f2bf(v.y); o.z = f2bf(v.z); o.w = f2bf(v.w);
    *(ushort4*)(dst + e) = o;
}

// ---------- GEMM: out[M,N] = A @ Bw^T + bias (+resid)(+relu) ----------
// 128x128 tile, BK=64, 4 waves. global_load_lds staging, pre-swizzled source.
// QKV mode: N=1536 segments -> Q(out0), K(out1), V transposed into vT(out2).
template<bool QKV, bool RELU, bool RESID, bool BF16OUT>
__global__ __launch_bounds__(256) void gemm_bt(
    const u16* __restrict__ A, const u16* __restrict__ Bw,
    const float* __restrict__ bias0, const float* __restrict__ bias1,
    const float* __restrict__ bias2, const float* __restrict__ resid,
    void* __restrict__ out0, void* __restrict__ out1, void* __restrict__ out2,
    int M, int N, int K)
{
    __shared__ __align__(16) u16 At[128 * 64];
    __shared__ __align__(16) u16 Bt[128 * 64];
    const int tid = threadIdx.x;
    const int l = tid & 63;
    const int w = tid >> 6;
    const int wr = w >> 1, wc = w & 1;
    const int mb = blockIdx.y, nb = blockIdx.x;

    const int lrow = l >> 3;
    const int lch  = (l & 7) ^ lrow;

    const u16* aTile = A  + (size_t)(mb * 128) * K + (size_t)lrow * K + lch * 8;
    const u16* bTile = Bw + (size_t)(nb * 128) * K + (size_t)lrow * K + lch * 8;

    f32x4 acc[4][4] = {};

    for (int k0 = 0; k0 < K; k0 += 64) {
        #pragma unroll
        for (int i = 0; i < 4; ++i) {
            int c = w * 4 + i;
            gld16(aTile + (size_t)(c * 8) * K + k0, &At[c * 512]);
            gld16(bTile + (size_t)(c * 8) * K + k0, &Bt[c * 512]);
        }
        __syncthreads();
        #pragma unroll
        for (int kc = 0; kc < 2; ++kc) {
            B8 af[4], bfr[4];
            #pragma unroll
            for (int m = 0; m < 4; ++m) {
                int r = wr * 64 + m * 16 + (l & 15);
                int ch = kc * 4 + (l >> 4);
                af[m].s = *(const s16x8*)&At[r * 64 + ((ch ^ (r & 7)) * 8)];
            }
            #pragma unroll
            for (int n = 0; n < 4; ++n) {
                int r = wc * 64 + n * 16 + (l & 15);
                int ch = kc * 4 + (l >> 4);
                bfr[n].s = *(const s16x8*)&Bt[r * 64 + ((ch ^ (r & 7)) * 8)];
            }
            #pragma unroll
            for (int m = 0; m < 4; ++m)
                #pragma unroll
                for (int n = 0; n < 4; ++n)
                    acc[m][n] = __builtin_amdgcn_mfma_f32_16x16x32_bf16(
                        af[m].b, bfr[n].b, acc[m][n], 0, 0, 0);
        }
        __syncthreads();
    }

    const float* biasp;
    void* outp;
    int colbase, Nout;
    if constexpr (QKV) {
        int which = nb >> 2;
        colbase = (nb & 3) * 128 + wc * 64;
        if (which == 2) {
            // V: write bf16 transposed into vT[bh][64 d][1024 s]
            float bcol[4];
            #pragma unroll
            for (int n = 0; n < 4; ++n)
                bcol[n] = bias2[colbase + n * 16 + (l & 15)];
            u16* vT = (u16*)out2;
            #pragma unroll
            for (int m = 0; m < 4; ++m) {
                int row0 = mb * 128 + wr * 64 + m * 16 + (l >> 4) * 4;
                int bb = row0 >> 10, s0 = row0 & 1023;
                #pragma unroll
                for (int n = 0; n < 4; ++n) {
                    int col = colbase + n * 16 + (l & 15);
                    int hh = col >> 6, dd = col & 63;
                    ushort4 o;
                    o.x = f2bf(acc[m][n][0] + bcol[n]);
                    o.y = f2bf(acc[m][n][1] + bcol[n]);
                    o.z = f2bf(acc[m][n][2] + bcol[n]);
                    o.w = f2bf(acc[m][n][3] + bcol[n]);
                    *(ushort4*)&vT[((size_t)((bb * 8 + hh) * 64 + dd)) * 1024 + s0] = o;
                }
            }
            return;
        }
        biasp = which == 0 ? bias0 : bias1;
        outp  = which == 0 ? out0  : out1;
        Nout = 512;
    } else {
        colbase = nb * 128 + wc * 64;
        biasp = bias0;
        outp = out0;
        Nout = N;
    }

    float bcol[4];
    #pragma unroll
    for (int n = 0; n < 4; ++n)
        bcol[n] = biasp[colbase + n * 16 + (l & 15)];

    #pragma unroll
    for (int m = 0; m < 4; ++m) {
        #pragma unroll
        for (int j = 0; j < 4; ++j) {
            int row = mb * 128 + wr * 64 + m * 16 + (l >> 4) * 4 + j;
            #pragma unroll
            for (int n = 0; n < 4; ++n) {
                int col = colbase + n * 16 + (l & 15);
                float v = acc[m][n][j] + bcol[n];
                if constexpr (RESID) v += resid[(size_t)row * Nout + col];
                if constexpr (RELU)  v = fmaxf(v, 0.0f);
                if constexpr (BF16OUT) ((u16*)outp)[(size_t)row * Nout + col] = f2bf(v);
                else                   ((float*)outp)[(size_t)row * Nout + col] = v;
            }
        }
    }
}

// ---------- LayerNorm ----------
__global__ __launch_bounds__(256) void ln_kernel(
    float* __restrict__ x, const float* __restrict__ g, const float* __restrict__ b,
    u16* __restrict__ xb)
{
    int row = blockIdx.x * 4 + (threadIdx.x >> 6);
    int l = threadIdx.x & 63;
    float4* xr = (float4*)(x + row * 512);
    float4 v0 = xr[l];
    float4 v1 = xr[l + 64];
    float s = v0.x + v0.y + v0.z + v0.w + v1.x + v1.y + v1.z + v1.w;
    float q = v0.x * v0.x + v0.y * v0.y + v0.z * v0.z + v0.w * v0.w
            + v1.x * v1.x + v1.y * v1.y + v1.z * v1.z + v1.w * v1.w;
    #pragma unroll
    for (int m = 1; m < 64; m <<= 1) {
        s += __shfl_xor(s, m, 64);
        q += __shfl_xor(q, m, 64);
    }
    float mean = s * (1.0f / 512.0f);
    float var  = q * (1.0f / 512.0f) - mean * mean;
    float rstd = rsqrtf(var + 1e-5f);
    const float4* gv = (const float4*)g;
    const float4* bv = (const float4*)b;
    float4 g0 = gv[l], g1 = gv[l + 64], b0 = bv[l], b1 = bv[l + 64];
    float4 o0, o1;
    o0.x = (v0.x - mean) * rstd * g0.x + b0.x;
    o0.y = (v0.y - mean) * rstd * g0.y + b0.y;
    o0.z = (v0.z - mean) * rstd * g0.z + b0.z;
    o0.w = (v0.w - mean) * rstd * g0.w + b0.w;
    o1.x = (v1.x - mean) * rstd * g1.x + b1.x;
    o1.y = (v1.y - mean) * rstd * g1.y + b1.y;
    o1.z = (v1.z - mean) * rstd * g1.z + b1.z;
    o1.w = (v1.w - mean) * rstd * g1.w + b1.w;
    xr[l] = o0; xr[l + 64] = o1;
    ushort4 h0, h1;
    h0.x = f2bf(o0.x); h0.y = f2bf(o0.y); h0.z = f2bf(o0.z); h0.w = f2bf(o0.w);
    h1.x = f2bf(o1.x); h1.y = f2bf(o1.y); h1.z = f2bf(o1.z); h1.w = f2bf(o1.w);
    ((ushort4*)(xb + row * 512))[l] = h0;
    ((ushort4*)(xb + row * 512))[l + 64] = h1;
}

// ---------- fused attention v3: swapped-operand flash, no K/V LDS, no barriers ----
// grid (64 bh, 8 qb), 256 threads = 4 independent waves; wave handles 32 q-rows.
// S^T = mfma(K, Q); softmax with q lane-local; O^T = mfma(vT, P^T);
// P exchanged through per-wave 4KB swizzled LDS.
__global__ __launch_bounds__(256) void attn_kernel(
    const u16* __restrict__ Q, const u16* __restrict__ Km,
    const u16* __restrict__ vT, u16* __restrict__ O)
{
    __shared__ __align__(16) char Pl[4][4096];
    const int tid = threadIdx.x;
    const int l = tid & 63;
    const int w = tid >> 6;
    const int g = l >> 4;            // lane group 0..3
    const int q15 = l & 15;
    const int bh = blockIdx.x;
    const int qb = blockIdx.y;
    const int b = bh >> 3, h = bh & 7;
    const int rowQ0 = b * 1024 + qb * 128 + w * 32;
    const int colh = h * 64;
    char* pl = &Pl[w][0];

    // Q as B-fragments (col=q, k=d), loaded once: qf[qt][kc]
    B8 qf[2][2];
    #pragma unroll
    for (int qt = 0; qt < 2; ++qt)
        #pragma unroll
        for (int kc = 0; kc < 2; ++kc)
            qf[qt][kc].s = *(const s16x8*)&Q[(size_t)(rowQ0 + qt * 16 + q15) * 512
                                            + colh + kc * 32 + g * 8];

    f32x4 oacc[4][4] = {};          // [dt][qt] used: [dt][0..1]; O^T[d][q]
    float mrun[2], lrun[2];
    mrun[0] = mrun[1] = -__builtin_huge_valf();
    lrun[0] = lrun[1] = 0.0f;

    const u16* Kb0 = Km + (size_t)(b * 1024) * 512 + colh;
    const u16* Vb0 = vT + (size_t)bh * 64 * 1024;

    for (int kt = 0; kt < 16; ++kt) {
        // --- S^T = K Q^T, st[qt][mt]: lane holds S^T[mt*16+g*4+jj][qt*16+q15]
        f32x4 st[2][4];
        #pragma unroll
        for (int mt = 0; mt < 4; ++mt) {
            B8 kf0, kf1;
            const u16* kr = Kb0 + (size_t)(kt * 64 + mt * 16 + q15) * 512;
            kf0.s = *(const s16x8*)(kr + g * 8);
            kf1.s = *(const s16x8*)(kr + 32 + g * 8);
            #pragma unroll
            for (int qt = 0; qt < 2; ++qt) {
                f32x4 t = {0.f, 0.f, 0.f, 0.f};
                t = __builtin_amdgcn_mfma_f32_16x16x32_bf16(kf0.b, qf[qt][0].b, t, 0, 0, 0);
                t = __builtin_amdgcn_mfma_f32_16x16x32_bf16(kf1.b, qf[qt][1].b, t, 0, 0, 0);
                st[qt][mt] = t * 0.125f;
            }
        }

        // --- online softmax (q = lane-local) + pack P into per-wave LDS
        #pragma unroll
        for (int qt = 0; qt < 2; ++qt) {
            float vm = st[qt][0][0];
            #pragma unroll
            for (int mt = 0; mt < 4; ++mt)
                #pragma unroll
                for (int jj = 0; jj < 4; ++jj)
                    vm = fmaxf(vm, st[qt][mt][jj]);
            vm = fmaxf(vm, __shfl_xor(vm, 16, 64));
            vm = fmaxf(vm, __shfl_xor(vm, 32, 64));
            float mn = fmaxf(mrun[qt], vm);
            float alpha = __expf(mrun[qt] - mn);
            mrun[qt] = mn;
            float rs = 0.0f;
            #pragma unroll
            for (int mt = 0; mt < 4; ++mt) {
                #pragma unroll
                for (int jj = 0; jj < 4; ++jj) {
                    float e = __expf(st[qt][mt][jj] - mn);
                    st[qt][mt][jj] = e;
                    rs += e;
                }
            }
            rs += __shfl_xor(rs, 16, 64);
            rs += __shfl_xor(rs, 32, 64);
            lrun[qt] = lrun[qt] * alpha + rs;
            #pragma unroll
            for (int dt = 0; dt < 4; ++dt)
                #pragma unroll
                for (int jj = 0; jj < 4; ++jj)
                    oacc[dt][qt][jj] *= alpha;

            // write P rows: P[q][k] row-major [32][64] u16, XOR-swizzled 16B blocks
            int qrow = qt * 16 + q15;
            int rbase = qrow * 128;
            int sw = (qrow & 7) << 4;
            #pragma unroll
            for (int mt = 0; mt < 4; ++mt) {
                uint2 pk;
                pk.x = pkbf(st[qt][mt][0], st[qt][mt][1]);
                pk.y = pkbf(st[qt][mt][2], st[qt][mt][3]);
                *(uint2*)(pl + rbase + ((mt * 32 + g * 8) ^ sw)) = pk;
            }
        }

        // --- O^T += vT-frag * P^T-frag
        B8 pf[2][2];
        #pragma unroll
        for (int qt = 0; qt < 2; ++qt) {
            int qrow = qt * 16 + q15;
            int sw = (qrow & 7) << 4;
            #pragma unroll
            for (int kc = 0; kc < 2; ++kc)
                pf[qt][kc].s = *(const s16x8*)(pl + qrow * 128 + (((kc * 4 + g) * 16) ^ sw));
        }
        #pragma unroll
        for (int dt = 0; dt < 4; ++dt) {
            const u16* vr = Vb0 + (size_t)(dt * 16 + q15) * 1024 + kt * 64;
            B8 vf0, vf1;
            vf0.s = *(const s16x8*)(vr + g * 8);
            vf1.s = *(const s16x8*)(vr + 32 + g * 8);
            #pragma unroll
            for (int qt = 0; qt < 2; ++qt) {
                oacc[dt][qt] = __builtin_amdgcn_mfma_f32_16x16x32_bf16(
                    vf0.b, pf[qt][0].b, oacc[dt][qt], 0, 0, 0);
                oacc[dt][qt] = __builtin_amdgcn_mfma_f32_16x16x32_bf16(
                    vf1.b, pf[qt][1].b, oacc[dt][qt], 0, 0, 0);
            }
        }
    }

    // --- epilogue: O[q][d] = O^T / l
    #pragma unroll
    for (int qt = 0; qt < 2; ++qt) {
        float inv = 1.0f / lrun[qt];
        int row = rowQ0 + qt * 16 + q15;
        #pragma unroll
        for (int dt = 0; dt < 4; ++dt) {
            ushort4 o;
            o.x = f2bf(oacc[dt][qt][0] * inv);
            o.y = f2bf(oacc[dt][qt][1] * inv);
            o.z = f2bf(oacc[dt][qt][2] * inv);
            o.w = f2bf(oacc[dt][qt][3] * inv);
            *(ushort4*)&O[(size_t)row * 512 + colh + dt * 16 + g * 4] = o;
        }
    }
}

// ---------- launcher ----------
extern "C" void kernel_launch(void* const* d_in, const int* in_sizes, int n_in,
                              void* d_out, int out_size, void* d_ws, size_t ws_size,
                              hipStream_t stream)
{
    const int D = 512, F = 2048, Lc = 4;
    const int Mrows = 8 * 1024;

    const float* Wq   = (const float*)d_in[1];
    const float* Wk   = (const float*)d_in[2];
    const float* Wv   = (const float*)d_in[3];
    const float* bq   = (const float*)d_in[4];
    const float* bk   = (const float*)d_in[5];
    const float* bv   = (const float*)d_in[6];
    const float* Wo   = (const float*)d_in[7];
    const float* bo   = (const float*)d_in[8];
    const float* ln1g = (const float*)d_in[9];
    const float* ln1b = (const float*)d_in[10];
    const float* ln2g = (const float*)d_in[11];
    const float* ln2b = (const float*)d_in[12];
    const float* W1   = (const float*)d_in[13];
    const float* b1   = (const float*)d_in[14];
    const float* W2   = (const float*)d_in[15];
    const float* b2   = (const float*)d_in[16];
    const float* Wout = (const float*)d_in[17];
    const float* bout = (const float*)d_in[18];

    char* p = (char*)d_ws;
    auto alloc = [&](size_t bytes) {
        char* r = p;
        p += (bytes + 255) & ~(size_t)255;
        return r;
    };
    float* xA = (float*)alloc((size_t)Mrows * D * 4);
    float* xB = (float*)alloc((size_t)Mrows * D * 4);
    u16* xb   = (u16*)alloc((size_t)Mrows * D * 2);
    char* pool = alloc((size_t)Mrows * F * 2);
    u16* qb_ = (u16*)pool;
    u16* kb_ = (u16*)(pool + (size_t)Mrows * D * 2);
    u16* vT  = (u16*)(pool + (size_t)Mrows * D * 2 * 2);   // [64 bh][64 d][1024 s]
    u16* ao  = (u16*)(pool + (size_t)Mrows * D * 2 * 3);
    u16* ff1 = (u16*)pool;
    u16* wqkvB = (u16*)alloc((size_t)Lc * 3 * D * D * 2);
    u16* woB   = (u16*)alloc((size_t)Lc * D * D * 2);
    u16* w1B   = (u16*)alloc((size_t)Lc * F * D * 2);
    u16* w2B   = (u16*)alloc((size_t)Lc * D * F * 2);
    u16* woutB = (u16*)alloc((size_t)D * D * 2);

    auto cvt = [&](const float* src, u16* dst, size_t n) {
        int n4 = (int)(n / 4);
        cvt_bf16_kernel<<<(n4 + 255) / 256, 256, 0, stream>>>(src, dst, n4);
    };
    {
        int n4 = Lc * 3 * D * D / 4;
        cvt_qkvw_kernel<<<(n4 + 255) / 256, 256, 0, stream>>>(Wq, Wk, Wv, wqkvB, n4);
    }
    cvt(Wo, woB, (size_t)Lc * D * D);
    cvt(W1, w1B, (size_t)Lc * F * D);
    cvt(W2, w2B, (size_t)Lc * D * F);
    cvt(Wout, woutB, (size_t)D * D);

    // DDIM noise coefficients
    float ac[1000];
    {
        float start = 1e-4f, stop = 0.02f;
        float delta = (stop - start) / 999.0f;
        float prod = 1.0f;
        for (int i = 0; i < 1000; ++i) {
            float beta = start + (float)i * delta;
            prod *= (1.0f - beta);
            ac[i] = prod;
        }
    }
    int ts[2] = {999, 998};
    double cs[2];
    double tail = 1.0;
    for (int idx = 0; idx < 2; ++idx) {
        int t = ts[idx];
        cs[idx] = sqrt(1.0 - (double)ac[t]) * tail;
        tail *= sqrt((double)ac[t]);
    }
    uint32_t kk[2][2];
    for (int idx = 0; idx < 2; ++idx) {
        uint32_t x0 = 0u, x1 = (uint32_t)ts[idx];
        tf2x32(0u, 42u, x0, x1);
        kk[idx][0] = x0; kk[idx][1] = x1;
    }
    int ntot = Mrows * D;
    noise_kernel<<<(ntot + 255) / 256, 256, 0, stream>>>(
        xA, xb,
        kk[0][0], kk[0][1], (float)cs[0],
        kk[1][0], kk[1][1], (float)cs[1], ntot);

    dim3 gqkv(3 * D / 128, Mrows / 128);
    dim3 g512(D / 128, Mrows / 128);
    dim3 gff1(F / 128, Mrows / 128);

    for (int l = 0; l < Lc; ++l) {
        const u16* wqkv_l = wqkvB + (size_t)l * 3 * D * D;
        const u16* wo_l = woB + (size_t)l * D * D;
        const u16* w1_l = w1B + (size_t)l * F * D;
        const u16* w2_l = w2B + (size_t)l * D * F;

        gemm_bt<true, false, false, true><<<gqkv, 256, 0, stream>>>(
            xb, wqkv_l, bq + l * D, bk + l * D, bv + l * D, nullptr,
            qb_, kb_, vT, Mrows, 3 * D, D);
        attn_kernel<<<dim3(64, 8), 256, 0, stream>>>(qb_, kb_, vT, ao);
        gemm_bt<false, false, true, false><<<g512, 256, 0, stream>>>(
            ao, wo_l, bo + l * D, nullptr, nullptr, xA,
            xB, nullptr, nullptr, Mrows, D, D);
        ln_kernel<<<Mrows / 4, 256, 0, stream>>>(xB, ln1g + l * D, ln1b + l * D, xb);
        gemm_bt<false, true, false, true><<<gff1, 256, 0, stream>>>(
            xb, w1_l, b1 + l * F, nullptr, nullptr, nullptr,
            ff1, nullptr, nullptr, Mrows, F, D);
        gemm_bt<false, false, true, false><<<g512, 256, 0, stream>>>(
            ff1, w2_l, b2 + l * D, nullptr, nullptr, xB,
            xA, nullptr, nullptr, Mrows, D, F);
        ln_kernel<<<Mrows / 4, 256, 0, stream>>>(xA, ln2g + l * D, ln2b + l * D, xb);
    }
    gemm_bt<false, false, false, false><<<g512, 256, 0, stream>>>(
        xb, woutB, bout, nullptr, nullptr, nullptr,
        d_out, nullptr, nullptr, Mrows, D, D);
}